// Round 1
// baseline (277.113 us; speedup 1.0000x reference)
//
#include <hip/hip_runtime.h>
#include <hip/hip_bf16.h>

#define WIDTH 1024
#define HEIGHT 1024

// Gaussian splat: each point scatters into a 5x5 neighborhood with
// separable exp(-50*d^2) weights, normalized per point over all 25 taps
// (normalizer = sumx*sumy by separability). Normalized weights below
// CUTOFF are skipped: only the 1-2 taps bracketing the point per axis
// survive (sigma=0.1), so ~2 atomics/point instead of 25.
#define CUTOFF 1e-10f

__global__ void __launch_bounds__(256)
splat_kernel(const float* __restrict__ x,
             const float* __restrict__ y,
             const float* __restrict__ v,
             float* __restrict__ out, int n) {
    int i = blockIdx.x * blockDim.x + threadIdx.x;
    if (i >= n) return;

    // DX = DY = 2/1024 = 2^-9, so (p - X0)/DX == (p + 1) * 512 exactly.
    float xp = (x[i] + 1.0f) * 512.0f;
    float yp = (y[i] + 1.0f) * 512.0f;
    int xb = (int)floorf(xp);
    int yb = (int)floorf(yp);
    float xf = xp - (float)xb;
    float yf = yp - (float)yb;

    float wx[5], wy[5];
    float sx = 0.0f, sy = 0.0f;
#pragma unroll
    for (int k = 0; k < 5; ++k) {
        float dx = xf - (float)(k - 2);
        float dy = yf - (float)(k - 2);
        wx[k] = __expf(-50.0f * dx * dx);
        wy[k] = __expf(-50.0f * dy * dy);
        sx += wx[k];
        sy += wy[k];
    }
    float inv_sx = 1.0f / sx;
    float inv_sy = 1.0f / sy;
    float val = v[i];

#pragma unroll
    for (int j = 0; j < 5; ++j) {
        int yi = yb + (j - 2);
        if (yi < 0 || yi >= HEIGHT) continue;
        float wyn = wy[j] * inv_sy;
        if (wyn < CUTOFF) continue;   // skips 3-4 of 5 rows
        float* row = out + yi * WIDTH;
        float vy = val * wyn;
#pragma unroll
        for (int k = 0; k < 5; ++k) {
            int xi = xb + (k - 2);
            if (xi < 0 || xi >= WIDTH) continue;
            float wn = wx[k] * inv_sx;
            if (wn < CUTOFF) continue;
            atomicAdd(row + xi, wn * vy);
        }
    }
}

extern "C" void kernel_launch(void* const* d_in, const int* in_sizes, int n_in,
                              void* d_out, int out_size, void* d_ws, size_t ws_size,
                              hipStream_t stream) {
    const float* x = (const float*)d_in[0];
    const float* y = (const float*)d_in[1];
    const float* v = (const float*)d_in[2];
    float* out = (float*)d_out;
    int n = in_sizes[0];

    // d_out is poisoned to 0xAA before every timed launch; zero it on-stream.
    hipMemsetAsync(out, 0, (size_t)out_size * sizeof(float), stream);

    int block = 256;
    int grid = (n + block - 1) / block;
    splat_kernel<<<grid, block, 0, stream>>>(x, y, v, out, n);
}